// Round 11
// baseline (381.567 us; speedup 1.0000x reference)
//
#include <hip/hip_runtime.h>

#define DFEAT 4096
#define NPAD 4224      // 4096 + 128 pad slots
#define NTH 512

typedef float2 cpx;

__device__ __forceinline__ cpx cmulf(cpx a, cpx b) {
  return make_float2(a.x * b.x - a.y * b.y, a.x * b.y + a.y * b.x);
}

// padded LDS index: +1 complex every 32 to break power-of-2 scatter strides
#define IDX(i) ((i) + ((i) >> 5))

// In-LDS 4096-pt complex FFT, radix-4 Stockham (auto-sorting), 512 threads.
// sgn = -1 forward, +1 inverse (unnormalized; 1/N folded into Ghat).
// Caller must __syncthreads() after filling b0. Result lands in b0 (natural order).
__device__ void fft4096(cpx* b0, cpx* b1, int tid, float sgn) {
  cpx* src = b0;
  cpx* dst = b1;
  for (int st = 0; st < 6; ++st) {
    const int Ns = 1 << (2 * st);
    const int sh = 2 * st;
#pragma unroll
    for (int q = 0; q < 2; ++q) {
      const int j = tid + (q << 9);        // 1024 butterflies/stage
      const int k = j & (Ns - 1);
      const int m = j >> sh;
      float ang = sgn * 6.28318530717958647692f * (float)k / (float)(Ns << 2);
      float s1, c1;
      __sincosf(ang, &s1, &c1);
      cpx w1 = make_float2(c1, s1);
      cpx w2 = cmulf(w1, w1);
      cpx w3 = cmulf(w2, w1);
      cpx v0 = src[IDX(j)];
      cpx v1 = cmulf(src[IDX(j + 1024)], w1);
      cpx v2 = cmulf(src[IDX(j + 2048)], w2);
      cpx v3 = cmulf(src[IDX(j + 3072)], w3);
      cpx t0 = make_float2(v0.x + v2.x, v0.y + v2.y);
      cpx t1 = make_float2(v0.x - v2.x, v0.y - v2.y);
      cpx t2 = make_float2(v1.x + v3.x, v1.y + v3.y);
      cpx t3 = make_float2(v1.x - v3.x, v1.y - v3.y);
      // y1 = t1 + sgn*i*t3 ; y3 = t1 - sgn*i*t3  (fwd: t1 - i t3)
      cpx it3 = make_float2(-sgn * t3.y, sgn * t3.x);
      const int d = (m << (sh + 2)) + k;
      dst[IDX(d)]          = make_float2(t0.x + t2.x, t0.y + t2.y);
      dst[IDX(d + Ns)]     = make_float2(t1.x + it3.x, t1.y + it3.y);
      dst[IDX(d + 2 * Ns)] = make_float2(t0.x - t2.x, t0.y - t2.y);
      dst[IDX(d + 3 * Ns)] = make_float2(t1.x - it3.x, t1.y - it3.y);
    }
    __syncthreads();
    cpx* tt = src; src = dst; dst = tt;
  }
  // 6 swaps (even) -> result in b0
}

// Ghat[r] = FFT(g[r]) / 4096, natural order, float2
__global__ __launch_bounds__(NTH) void ghat_kernel(const float* __restrict__ g,
                                                   cpx* __restrict__ Ghat) {
  __shared__ cpx B0[NPAD], B1[NPAD];
  const int r = blockIdx.x;
  const int tid = threadIdx.x;
#pragma unroll
  for (int q = 0; q < 8; ++q) {
    int i = tid + (q << 9);
    B0[IDX(i)] = make_float2(g[r * DFEAT + i], 0.0f);
  }
  __syncthreads();
  fft4096(B0, B1, tid, -1.0f);
  const float inv = 1.0f / 4096.0f;
#pragma unroll
  for (int q = 0; q < 8; ++q) {
    int i = tid + (q << 9);
    cpx v = B0[IDX(i)];
    Ghat[r * DFEAT + i] = make_float2(v.x * inv, v.y * inv);
  }
}

// One block = one row PAIR (two-for-one real conv):
//   w = x1*psi + i*x2*psi ; W = FFT(w)
//   for r: z = IFFT(W * Ghat_r) ; y1 += Re(z)*omega_r ; y2 += Im(z)*omega_r
__global__ __launch_bounds__(NTH) void fftconv_kernel(
    const float* __restrict__ x, const float* __restrict__ psi,
    const float* __restrict__ omega, const float* __restrict__ bias,
    const cpx* __restrict__ Ghat, float* __restrict__ out) {
  __shared__ cpx B0[NPAD], B1[NPAD];
  const int p = blockIdx.x;
  const int tid = threadIdx.x;
  const float* x1 = x + ((size_t)(2 * p)) * DFEAT;
  const float* x2 = x1 + DFEAT;

#pragma unroll
  for (int q = 0; q < 8; ++q) {
    int i = tid + (q << 9);
    float ps = psi[i];
    B0[IDX(i)] = make_float2(x1[i] * ps, x2[i] * ps);
  }
  __syncthreads();
  fft4096(B0, B1, tid, -1.0f);

  cpx Wr[8];
#pragma unroll
  for (int q = 0; q < 8; ++q) Wr[q] = B0[IDX(tid + (q << 9))];

  float a1[8] = {0, 0, 0, 0, 0, 0, 0, 0};
  float a2[8] = {0, 0, 0, 0, 0, 0, 0, 0};

  for (int r = 0; r < 3; ++r) {
    __syncthreads();   // everyone done reading B0 (Wr / prev accumulate)
#pragma unroll
    for (int q = 0; q < 8; ++q) {
      int i = tid + (q << 9);
      B0[IDX(i)] = cmulf(Wr[q], Ghat[r * DFEAT + i]);
    }
    __syncthreads();
    fft4096(B0, B1, tid, 1.0f);
#pragma unroll
    for (int q = 0; q < 8; ++q) {
      int i = tid + (q << 9);
      cpx z = B0[IDX(i)];
      float om = omega[r * DFEAT + i];
      a1[q] += z.x * om;
      a2[q] += z.y * om;
    }
  }

  float* o1 = out + ((size_t)(2 * p)) * DFEAT;
#pragma unroll
  for (int q = 0; q < 8; ++q) {
    int i = tid + (q << 9);
    float b = bias[i];
    o1[i] = a1[q] + b;
    o1[DFEAT + i] = a2[q] + b;
  }
}

extern "C" void kernel_launch(void* const* d_in, const int* in_sizes, int n_in,
                              void* d_out, int out_size, void* d_ws, size_t ws_size,
                              hipStream_t stream) {
  const float* x     = (const float*)d_in[0];
  const float* psi   = (const float*)d_in[1];
  const float* omega = (const float*)d_in[2];
  const float* g     = (const float*)d_in[3];
  const float* bias  = (const float*)d_in[4];

  const int M = in_sizes[0] / DFEAT;   // 8192 rows

  cpx* Ghat = (cpx*)d_ws;              // 3 * 4096 * 8B = 96 KB

  ghat_kernel<<<3, NTH, 0, stream>>>(g, Ghat);
  fftconv_kernel<<<M / 2, NTH, 0, stream>>>(x, psi, omega, bias, Ghat,
                                            (float*)d_out);
}

// Round 12
// 307.341 us; speedup vs baseline: 1.2415x; 1.2415x over previous
//
#include <hip/hip_runtime.h>

#define DFEAT 4096
#define NPAD 4224      // 4096 + 128 pad slots
#define NTH 512

typedef float2 cpx;

__device__ __forceinline__ cpx cmulf(cpx a, cpx b) {
  return make_float2(a.x * b.x - a.y * b.y, a.x * b.y + a.y * b.x);
}

// padded LDS index: +1 complex every 32 to break power-of-2 scatter strides
#define IDX(i) ((i) + ((i) >> 5))

// sin/cos with argument in REVOLUTIONS (hardware v_sin_f32 semantics).
// Inputs here are always in [0, 0.25) — no range reduction needed.
__device__ __forceinline__ float sin_rev(float rev) {
#if __has_builtin(__builtin_amdgcn_sinf)
  return __builtin_amdgcn_sinf(rev);
#else
  return __sinf(rev * 6.28318530717958647692f);
#endif
}
__device__ __forceinline__ float cos_rev(float rev) {
#if __has_builtin(__builtin_amdgcn_cosf)
  return __builtin_amdgcn_cosf(rev);
#else
  return __cosf(rev * 6.28318530717958647692f);
#endif
}

// In-LDS 4096-pt complex FFT, radix-4 Stockham (auto-sorting), 512 threads.
// INV=0 forward, INV=1 inverse (unnormalized; 1/N folded into Ghat).
// Stage loop fully unrolled: Ns compile-time, twiddle angle = k * const,
// stage-0 twiddles fold to identity. Result lands in b0 (natural order).
template <int INV>
__device__ __forceinline__ void fft4096(cpx* b0, cpx* b1, int tid) {
  cpx* src = b0;
  cpx* dst = b1;
#pragma unroll
  for (int st = 0; st < 6; ++st) {
    const int Ns = 1 << (2 * st);
    const int sh = 2 * st;
#pragma unroll
    for (int q = 0; q < 2; ++q) {
      const int j = tid + (q << 9);        // 1024 butterflies/stage
      const int k = j & (Ns - 1);
      const int m = j >> sh;
      const float rev = (float)k * (0.25f / (float)Ns);   // in [0, 0.25)
      float s1 = sin_rev(rev);
      float c1 = cos_rev(rev);
      if (!INV) s1 = -s1;                  // fwd: w = exp(-i 2π rev)
      cpx w1 = make_float2(c1, s1);
      cpx w2 = cmulf(w1, w1);
      cpx w3 = cmulf(w2, w1);
      cpx v0 = src[IDX(j)];
      cpx v1 = cmulf(src[IDX(j + 1024)], w1);
      cpx v2 = cmulf(src[IDX(j + 2048)], w2);
      cpx v3 = cmulf(src[IDX(j + 3072)], w3);
      cpx t0 = make_float2(v0.x + v2.x, v0.y + v2.y);
      cpx t1 = make_float2(v0.x - v2.x, v0.y - v2.y);
      cpx t2 = make_float2(v1.x + v3.x, v1.y + v3.y);
      cpx t3 = make_float2(v1.x - v3.x, v1.y - v3.y);
      // y1 = t1 + sgn*i*t3 ; y3 = t1 - sgn*i*t3  (sgn=-1 fwd, +1 inv)
      cpx it3 = INV ? make_float2(-t3.y, t3.x) : make_float2(t3.y, -t3.x);
      const int d = (m << (sh + 2)) + k;
      dst[IDX(d)]          = make_float2(t0.x + t2.x, t0.y + t2.y);
      dst[IDX(d + Ns)]     = make_float2(t1.x + it3.x, t1.y + it3.y);
      dst[IDX(d + 2 * Ns)] = make_float2(t0.x - t2.x, t0.y - t2.y);
      dst[IDX(d + 3 * Ns)] = make_float2(t1.x - it3.x, t1.y - it3.y);
    }
    __syncthreads();
    cpx* tt = src; src = dst; dst = tt;
  }
  // 6 swaps (even) -> result in b0
}

// Ghat[r] = FFT(g[r]) / 4096, natural order, float2
__global__ __launch_bounds__(NTH) void ghat_kernel(const float* __restrict__ g,
                                                   cpx* __restrict__ Ghat) {
  __shared__ cpx B0[NPAD], B1[NPAD];
  const int r = blockIdx.x;
  const int tid = threadIdx.x;
#pragma unroll
  for (int q = 0; q < 8; ++q) {
    int i = tid + (q << 9);
    B0[IDX(i)] = make_float2(g[r * DFEAT + i], 0.0f);
  }
  __syncthreads();
  fft4096<0>(B0, B1, tid);
  const float inv = 1.0f / 4096.0f;
#pragma unroll
  for (int q = 0; q < 8; ++q) {
    int i = tid + (q << 9);
    cpx v = B0[IDX(i)];
    Ghat[r * DFEAT + i] = make_float2(v.x * inv, v.y * inv);
  }
}

// One block = one row PAIR (two-for-one real conv):
//   w = x1*psi + i*x2*psi ; W = FFT(w)
//   for r: z = IFFT(W * Ghat_r) ; y1 += Re(z)*omega_r ; y2 += Im(z)*omega_r
__global__ __launch_bounds__(NTH) void fftconv_kernel(
    const float* __restrict__ x, const float* __restrict__ psi,
    const float* __restrict__ omega, const float* __restrict__ bias,
    const cpx* __restrict__ Ghat, float* __restrict__ out) {
  __shared__ cpx B0[NPAD], B1[NPAD];
  const int p = blockIdx.x;
  const int tid = threadIdx.x;
  const float* x1 = x + ((size_t)(2 * p)) * DFEAT;
  const float* x2 = x1 + DFEAT;

#pragma unroll
  for (int q = 0; q < 8; ++q) {
    int i = tid + (q << 9);
    float ps = psi[i];
    B0[IDX(i)] = make_float2(x1[i] * ps, x2[i] * ps);
  }
  __syncthreads();
  fft4096<0>(B0, B1, tid);

  cpx Wr[8];
#pragma unroll
  for (int q = 0; q < 8; ++q) Wr[q] = B0[IDX(tid + (q << 9))];

  float a1[8] = {0, 0, 0, 0, 0, 0, 0, 0};
  float a2[8] = {0, 0, 0, 0, 0, 0, 0, 0};

  for (int r = 0; r < 3; ++r) {
    __syncthreads();   // everyone done reading B0 (Wr / prev accumulate)
#pragma unroll
    for (int q = 0; q < 8; ++q) {
      int i = tid + (q << 9);
      B0[IDX(i)] = cmulf(Wr[q], Ghat[r * DFEAT + i]);
    }
    __syncthreads();
    fft4096<1>(B0, B1, tid);
#pragma unroll
    for (int q = 0; q < 8; ++q) {
      int i = tid + (q << 9);
      cpx z = B0[IDX(i)];
      float om = omega[r * DFEAT + i];
      a1[q] += z.x * om;
      a2[q] += z.y * om;
    }
  }

  float* o1 = out + ((size_t)(2 * p)) * DFEAT;
#pragma unroll
  for (int q = 0; q < 8; ++q) {
    int i = tid + (q << 9);
    float b = bias[i];
    o1[i] = a1[q] + b;
    o1[DFEAT + i] = a2[q] + b;
  }
}

extern "C" void kernel_launch(void* const* d_in, const int* in_sizes, int n_in,
                              void* d_out, int out_size, void* d_ws, size_t ws_size,
                              hipStream_t stream) {
  const float* x     = (const float*)d_in[0];
  const float* psi   = (const float*)d_in[1];
  const float* omega = (const float*)d_in[2];
  const float* g     = (const float*)d_in[3];
  const float* bias  = (const float*)d_in[4];

  const int M = in_sizes[0] / DFEAT;   // 8192 rows

  cpx* Ghat = (cpx*)d_ws;              // 3 * 4096 * 8B = 96 KB

  ghat_kernel<<<3, NTH, 0, stream>>>(g, Ghat);
  fftconv_kernel<<<M / 2, NTH, 0, stream>>>(x, psi, omega, bias, Ghat,
                                            (float*)d_out);
}